// Round 1
// baseline (331.335 us; speedup 1.0000x reference)
//
#include <hip/hip_runtime.h>
#include <math.h>

#define NBATCH 4096
#define TNUM   128
#define NVARC  16
#define NOBSC  10
#define MAXIT  30

// ws layout (floats)
#define WS_MX  0      // 16x16
#define WS_MY  256    // 16x16
#define WS_NX  512    // 16x8
#define WS_NY  640    // 16x9
#define WS_NX0 784    // 16x8
#define WS_NY0 912    // 16x9
// total 1056 floats

// ---------------- setup kernel: build + invert KKT matrices (fp64 GJ) -------
__global__ __launch_bounds__(64) void planner_setup(
    const float* __restrict__ P, const float* __restrict__ Pd, const float* __restrict__ Pdd,
    float* __restrict__ ws)
{
  const int mid = blockIdx.x;   // 0: (cost_sm,Ax)->Nx0  1: (cost_sm,Ay)->Ny0
                                // 2: (cost_x,Ax)->Mx,Nx 3: (cost_y,Ay)->My,Ny
  const int tid = threadIdx.x;
  __shared__ double C[16][16];
  __shared__ double Ae[9][16];
  __shared__ double aug[25][50];
  __shared__ int pivs;

  const bool isY = (mid & 1);
  const int  m   = isY ? 9 : 8;
  const int  n   = 16 + m;
  const int  w   = 2 * n;

  // Gram matrices + cost matrix
  for (int e = tid; e < 256; e += 64) {
    const int j = e >> 4, k = e & 15;
    double gdd = 0.0, gd = 0.0, g0 = 0.0;
    for (int t = 0; t < TNUM; ++t) {
      gdd += (double)Pdd[t*16+j] * (double)Pdd[t*16+k];
      gd  += (double)Pd [t*16+j] * (double)Pd [t*16+k];
      g0  += (double)P  [t*16+j] * (double)P  [t*16+k];
    }
    double cs = 100.0 * (gdd + ((j == k) ? 0.1 : 0.0));   // cost_sm
    double c  = cs;
    if (mid >= 2) {
      c = cs + gdd + gd + 10.0 * g0;                      // cost_x
      if (mid == 3) c += 2.0 * g0;                        // cost_y
    }
    C[j][k] = c;
  }
  if (tid < 16) {
    const int j = tid;
    Ae[0][j] = (double)P  [0*16+j];
    Ae[1][j] = (double)Pd [0*16+j];
    Ae[2][j] = (double)Pdd[0*16+j];
    if (!isY) {
      Ae[3][j] = (double)Pd[127*16+j];
      for (int r = 4; r < 8; ++r) Ae[r][j] = (j == r) ? 1.0 : 0.0;
    } else {
      Ae[3][j] = (double)P [127*16+j];
      Ae[4][j] = (double)Pd[127*16+j];
      for (int r = 5; r < 9; ++r) Ae[r][j] = (j == (r-1)) ? 1.0 : 0.0;
    }
  }
  __syncthreads();

  // build augmented [KKT | I]
  for (int e = tid; e < n * w; e += 64) {
    const int r = e / w, c = e % w;
    double val;
    if (c < n) {
      if (r < 16) val = (c < 16) ? C[r][c] : Ae[c-16][r];
      else        val = (c < 16) ? Ae[r-16][c] : 0.0;
    } else {
      val = ((c - n) == r) ? 1.0 : 0.0;
    }
    aug[r][c] = val;
  }
  __syncthreads();

  // Gauss-Jordan with partial pivoting
  for (int k = 0; k < n; ++k) {
    if (tid == 0) {
      int p = k; double best = fabs(aug[k][k]);
      for (int r = k+1; r < n; ++r) { double a = fabs(aug[r][k]); if (a > best) { best = a; p = r; } }
      pivs = p;
    }
    __syncthreads();
    const int p = pivs;
    if (p != k) {
      for (int c = tid; c < w; c += 64) { double t = aug[k][c]; aug[k][c] = aug[p][c]; aug[p][c] = t; }
    }
    __syncthreads();
    const double ipiv = 1.0 / aug[k][k];
    __syncthreads();
    for (int c = tid; c < w; c += 64) aug[k][c] *= ipiv;
    __syncthreads();
    for (int r = tid; r < n; r += 64) {
      if (r != k) {
        const double f = aug[r][k];
        for (int c = k; c < w; ++c) aug[r][c] -= f * aug[k][c];
      }
    }
    __syncthreads();
  }

  // write needed sub-blocks of the inverse (cols n.. of aug)
  if (mid == 0) {
    for (int e = tid; e < 16*8; e += 64) ws[WS_NX0 + e] = (float)aug[e >> 3][n + 16 + (e & 7)];
  } else if (mid == 1) {
    for (int e = tid; e < 16*9; e += 64) ws[WS_NY0 + e] = (float)aug[e / 9][n + 16 + (e % 9)];
  } else if (mid == 2) {
    for (int e = tid; e < 256;  e += 64) ws[WS_MX + e] = (float)aug[e >> 4][n + (e & 15)];
    for (int e = tid; e < 16*8; e += 64) ws[WS_NX + e] = (float)aug[e >> 3][n + 16 + (e & 7)];
  } else {
    for (int e = tid; e < 256;  e += 64) ws[WS_MY + e] = (float)aug[e >> 4][n + (e & 15)];
    for (int e = tid; e < 16*9; e += 64) ws[WS_NY + e] = (float)aug[e / 9][n + 16 + (e % 9)];
  }
}

// ---------------- main kernel: one wave per batch element -------------------
__global__ __launch_bounds__(64, 2) void planner_main(
    const float* __restrict__ P, const float* __restrict__ Pd, const float* __restrict__ Pdd,
    const float* __restrict__ init_state, const float* __restrict__ fin_state,
    const float* __restrict__ cobs, const float* __restrict__ vobs,
    const float* __restrict__ yub_g, const float* __restrict__ ylb_g,
    const float* __restrict__ lamx_g, const float* __restrict__ lamy_g,
    const float* __restrict__ cxp_g, const float* __restrict__ cyp_g,
    const float* __restrict__ ws, float* __restrict__ out)
{
  const int b    = blockIdx.x;
  const int lane = threadIdx.x;

  __shared__ float red[64*64];
  __shared__ float MxL[256];
  __shared__ float MyL[256];
  __shared__ alignas(16) float cxL[16];
  __shared__ alignas(16) float cyL[16];
  __shared__ float gL[32];

  // basis rows for this lane's two timesteps (t = lane, lane+64)
  float Pr[2][16], Pdr[2][16], Pddr[2][16];
  #pragma unroll
  for (int u = 0; u < 2; ++u) {
    const int t = lane + 64*u;
    #pragma unroll
    for (int q = 0; q < 4; ++q) {
      const float4 a  = *reinterpret_cast<const float4*>(P   + t*16 + 4*q);
      const float4 bb = *reinterpret_cast<const float4*>(Pd  + t*16 + 4*q);
      const float4 cc = *reinterpret_cast<const float4*>(Pdd + t*16 + 4*q);
      Pr  [u][4*q+0] = a.x;  Pr  [u][4*q+1] = a.y;  Pr  [u][4*q+2] = a.z;  Pr  [u][4*q+3] = a.w;
      Pdr [u][4*q+0] = bb.x; Pdr [u][4*q+1] = bb.y; Pdr [u][4*q+2] = bb.z; Pdr [u][4*q+3] = bb.w;
      Pddr[u][4*q+0] = cc.x; Pddr[u][4*q+1] = cc.y; Pddr[u][4*q+2] = cc.z; Pddr[u][4*q+3] = cc.w;
    }
  }

  // obstacle trajectories for this lane's two timesteps (constant over iters)
  float xot[2][10], yot[2][10];
  {
    const float tt0 = (float)lane        * (10.0f/127.0f);
    const float tt1 = (float)(lane + 64) * (10.0f/127.0f);
    #pragma unroll
    for (int o = 0; o < NOBSC; ++o) {
      const float xo  = cobs[b*20 + o],  yo  = cobs[b*20 + 10 + o];
      const float vxo = vobs[b*20 + o],  vyo = vobs[b*20 + 10 + o];
      xot[0][o] = xo + vxo*tt0;  xot[1][o] = xo + vxo*tt1;
      yot[0][o] = yo + vyo*tt0;  yot[1][o] = yo + vyo*tt1;
    }
  }
  const float yub = yub_g[b], ylb = ylb_g[b];

  // b_eq vectors (uniform across lanes)
  float beqx[8], beqy[9];
  {
    const float xi  = init_state[b*4+0], yi  = init_state[b*4+1];
    const float vi  = init_state[b*4+2], psi = init_state[b*4+3];
    const float vxi = vi * cosf(psi),    vyi = vi * sinf(psi);
    const float xf  = fin_state[b*3+0],  yf  = fin_state[b*3+1];
    beqx[0]=xi; beqx[1]=vxi; beqx[2]=0.f; beqx[3]=xf;
    beqy[0]=yi; beqy[1]=vyi; beqy[2]=0.f; beqy[3]=yf; beqy[4]=0.f;
    #pragma unroll
    for (int i = 0; i < 4; ++i) { beqx[4+i] = cxp_g[b*4+i]; beqy[5+i] = cyp_g[b*4+i]; }
  }

  // stage Mx/My into LDS
  for (int i = lane; i < 256; i += 64) { MxL[i] = ws[WS_MX + i]; MyL[i] = ws[WS_MY + i]; }

  // per-lane constants: const term of the solve, initial primal, lambda carry
  float constv = 0.f, lam = 0.f;
  if (lane < 16) {
    float c0 = 0.f;
    #pragma unroll
    for (int mm = 0; mm < 8; ++mm) {
      constv += ws[WS_NX  + lane*8 + mm] * beqx[mm];
      c0     += ws[WS_NX0 + lane*8 + mm] * beqx[mm];
    }
    cxL[lane] = c0;
    lam = lamx_g[b*16 + lane];
  } else if (lane < 32) {
    const int j = lane - 16;
    float c0 = 0.f;
    #pragma unroll
    for (int mm = 0; mm < 9; ++mm) {
      constv += ws[WS_NY  + j*9 + mm] * beqy[mm];
      c0     += ws[WS_NY0 + j*9 + mm] * beqy[mm];
    }
    cyL[j] = c0;
  } else if (lane < 48) {
    lam = lamy_g[b*16 + (lane - 32)];
  }

  #pragma unroll 1
  for (int it = 0; it < MAXIT; ++it) {
    __syncthreads();

    // broadcast-read primal coefficients
    float cxv[16], cyv[16];
    #pragma unroll
    for (int q = 0; q < 4; ++q) {
      const float4 t1 = reinterpret_cast<const float4*>(cxL)[q];
      const float4 t2 = reinterpret_cast<const float4*>(cyL)[q];
      cxv[4*q+0]=t1.x; cxv[4*q+1]=t1.y; cxv[4*q+2]=t1.z; cxv[4*q+3]=t1.w;
      cyv[4*q+0]=t2.x; cyv[4*q+1]=t2.y; cyv[4*q+2]=t2.z; cyv[4*q+3]=t2.w;
    }

    float v[64];
    #pragma unroll
    for (int i = 0; i < 64; ++i) v[i] = 0.f;

    #pragma unroll
    for (int u = 0; u < 2; ++u) {
      float x=0.f, xd=0.f, xdd=0.f, y=0.f, yd=0.f, ydd=0.f;
      #pragma unroll
      for (int j = 0; j < 16; ++j) {
        const float cj = cxv[j], dj = cyv[j];
        x   += Pr  [u][j]*cj;   y   += Pr  [u][j]*dj;
        xd  += Pdr [u][j]*cj;   yd  += Pdr [u][j]*dj;
        xdd += Pddr[u][j]*cj;   ydd += Pddr[u][j]*dj;
      }
      // accel projection: g_a = min(1, A_MAX/|a|)
      const float ria = rsqrtf(fmaxf(xdd*xdd + ydd*ydd, 1e-36f));
      const float ga  = fminf(1.f, 18.f * ria);
      // vel projection: g_v = clip(|v|, V_MIN, V_MAX)/|v|
      const float riv = rsqrtf(fmaxf(xd*xd + yd*yd, 1e-36f));
      const float gv  = fminf(fmaxf(1.f, 0.1f * riv), 30.f * riv);
      // obstacles: e = max(0, AB/r - 1), r = hypot(A*ws, B*wc)
      float Sx = 0.f, Sy = 0.f;
      #pragma unroll
      for (int o = 0; o < NOBSC; ++o) {
        const float wc  = x - xot[u][o];
        const float wsv = y - yot[u][o];
        const float aw = 6.0f * wsv, bw = 3.2f * wc;
        const float e = fmaxf(0.f, 19.2f * rsqrtf(fmaxf(aw*aw + bw*bw, 1e-36f)) - 1.f);
        Sx += e * wc; Sy += e * wsv;
      }
      // lane constraints
      const float rln = fmaxf(y - yub, 0.f) - fmaxf(ylb - y, 0.f);
      const float lln = fminf(y, yub) + fmaxf(y, ylb);

      const float c0dd = xdd - xdd*ga, c0d = xd - xd*gv, c0p = -Sx;
      const float c1dd = xdd*ga,       c1d = xd*gv,      c1p = 10.f*x + Sx;
      const float c2dd = ydd - ydd*ga, c2d = yd - yd*gv, c2p = rln - Sy;
      const float c3dd = ydd*ga,       c3d = yd*gv,      c3p = 10.f*y + Sy + lln;

      #pragma unroll
      for (int j = 0; j < 16; ++j) {
        const float bp = Pr[u][j], bd = Pdr[u][j], bdd = Pddr[u][j];
        v[j]      += c0dd*bdd + c0d*bd + c0p*bp;   // dlx
        v[16 + j] += c1dd*bdd + c1d*bd + c1p*bp;   // gx extra
        v[32 + j] += c2dd*bdd + c2d*bd + c2p*bp;   // dly
        v[48 + j] += c3dd*bdd + c3d*bd + c3p*bp;   // gy extra
      }
    }

    // cross-lane reduction via LDS transpose (conflict-free rotation reads)
    #pragma unroll
    for (int i = 0; i < 64; ++i) red[i*64 + lane] = v[i];
    __syncthreads();
    float s = 0.f;
    const int base = lane * 64;
    #pragma unroll
    for (int k = 0; k < 64; ++k) s += red[base + ((lane + k) & 63)];

    // lambda update + g assembly (lane o holds SUM[o], o = vec*16+j)
    const float recv = __shfl_xor(s, 16);
    if (lane < 16) {
      lam -= s;                    // lx_new
      gL[lane] = lam + recv;       // gx = lx_new + gx_extra
    } else if (lane >= 32 && lane < 48) {
      lam -= s;                    // ly_new
      gL[lane - 16] = lam + recv;  // gy
    }
    __syncthreads();

    // primal solve: c = M*g + const
    if (lane < 16) {
      float acc = constv;
      #pragma unroll
      for (int k2 = 0; k2 < 16; ++k2) acc += MxL[lane*16 + k2] * gL[k2];
      cxL[lane] = acc;
    } else if (lane < 32) {
      const int j = lane - 16;
      float acc = constv;
      #pragma unroll
      for (int k2 = 0; k2 < 16; ++k2) acc += MyL[j*16 + k2] * gL[16 + k2];
      cyL[j] = acc;
    }
  }
  __syncthreads();
  if (lane < 32) out[b*32 + lane] = (lane < 16) ? cxL[lane] : cyL[lane - 16];
}

extern "C" void kernel_launch(void* const* d_in, const int* in_sizes, int n_in,
                              void* d_out, int out_size, void* d_ws, size_t ws_size,
                              hipStream_t stream) {
  const float* P    = (const float*)d_in[0];
  const float* Pd   = (const float*)d_in[1];
  const float* Pdd  = (const float*)d_in[2];
  const float* init = (const float*)d_in[3];
  const float* fin  = (const float*)d_in[4];
  const float* cobs = (const float*)d_in[5];
  const float* vobs = (const float*)d_in[6];
  const float* yub  = (const float*)d_in[7];
  const float* ylb  = (const float*)d_in[8];
  const float* lamx = (const float*)d_in[9];
  const float* lamy = (const float*)d_in[10];
  const float* cxp  = (const float*)d_in[11];
  const float* cyp  = (const float*)d_in[12];
  float* ws  = (float*)d_ws;
  float* o   = (float*)d_out;

  planner_setup<<<dim3(4), dim3(64), 0, stream>>>(P, Pd, Pdd, ws);
  planner_main<<<dim3(NBATCH), dim3(64), 0, stream>>>(
      P, Pd, Pdd, init, fin, cobs, vobs, yub, ylb, lamx, lamy, cxp, cyp, ws, o);
}